// Round 13
// baseline (97.600 us; speedup 1.0000x reference)
//
#include <hip/hip_runtime.h>

typedef unsigned short u16;
typedef unsigned int u32;
typedef __attribute__((ext_vector_type(8))) short short8;
typedef __attribute__((ext_vector_type(4))) float f32x4;

__device__ __forceinline__ u16 f2b(float f) {
  u32 u = __builtin_bit_cast(u32, f);
  u32 r = (u + 0x7FFFu + ((u >> 16) & 1u)) >> 16;  // RNE f32->bf16
  return (u16)r;
}

__device__ __forceinline__ void gl_lds16(const void* g, void* l) {
  __builtin_amdgcn_global_load_lds(
      (const __attribute__((address_space(1))) u32*)g,
      (__attribute__((address_space(3))) u32*)l, 16, 0, 0);
}

struct Ptrs8 { const float* p[8]; };

// ---------------------------------------------------------------------------
// Fused pre-pass (one launch):
//   bid <  2048 : wt_pack  — Wt[g*1024+n][h*1024+k] = bf16(W[h*4+g][k][n])
//   2048..6143  : xh_pack  — Ap[m][k] = bf16(k<1024 ? x[m][k] : h0[m][k-1024])
//   6144..6159  : bias     — bias[g*1024+n] = b_in + b_hid (f32)
// ---------------------------------------------------------------------------
__global__ __launch_bounds__(256) void prepack(Ptrs8 w, Ptrs8 b,
                                               const float* __restrict__ x,
                                               const float* __restrict__ h0,
                                               u16* __restrict__ Wt,
                                               u16* __restrict__ Ap,
                                               float* __restrict__ bias) {
  __shared__ float lds[64 * 64];     // 16 KB (used by wt branch only)
  const int tid = threadIdx.x;
  const int bid = blockIdx.x;

  if (bid < 2048) {                       // ---- wt_pack ----
    const int mat = bid >> 8;             // 0..7
    const int g = mat & 3, h = mat >> 2;
    const int tile = bid & 255;
    const int kt = tile >> 4, nt = tile & 15;
    const float* __restrict__ src = w.p[mat];
#pragma unroll
    for (int i = 0; i < 4; ++i) {
      int c = tid + i * 256;
      int k = c >> 4, n4 = (c & 15) * 4;
      gl_lds16(src + (size_t)(kt * 64 + k) * 1024 + nt * 64 + n4, &lds[c * 4]);
    }
    asm volatile("s_waitcnt vmcnt(0)");
    __syncthreads();
#pragma unroll
    for (int i = 0; i < 2; ++i) {
      int c = tid + i * 256;
      int n = c & 63, kb = (c >> 6) * 8;
      short8 v;
#pragma unroll
      for (int j = 0; j < 8; ++j) v[j] = (short)f2b(lds[(kb + j) * 64 + n]);
      size_t off = (size_t)(g * 1024 + nt * 64 + n) * 2048 + h * 1024 + kt * 64 + kb;
      *reinterpret_cast<short8*>(Wt + off) = v;
    }
  } else if (bid < 6144) {                // ---- xh_pack ----
    int t = (bid - 2048) * 256 + tid;
    int m = t >> 8, kc = t & 255;
    const float* src = (kc < 128) ? (x + (size_t)m * 1024 + kc * 8)
                                  : (h0 + (size_t)m * 1024 + (kc - 128) * 8);
    float4 a = *reinterpret_cast<const float4*>(src);
    float4 bb = *reinterpret_cast<const float4*>(src + 4);
    short8 v;
    v[0] = (short)f2b(a.x); v[1] = (short)f2b(a.y);
    v[2] = (short)f2b(a.z); v[3] = (short)f2b(a.w);
    v[4] = (short)f2b(bb.x); v[5] = (short)f2b(bb.y);
    v[6] = (short)f2b(bb.z); v[7] = (short)f2b(bb.w);
    *reinterpret_cast<short8*>(Ap + (size_t)m * 2048 + kc * 8) = v;
  } else {                                // ---- bias ----
    int i = (bid - 6144) * 256 + tid;     // 0..4095
    int g = i >> 10, n = i & 1023;
    bias[i] = b.p[g][n] + b.p[4 + g][n];
  }
}

// ---------------------------------------------------------------------------
// Fused LSTM GEMM — 2 blocks/CU cross-block overlap:
// 256 thr / 4 waves (2M x 2N), block 256m x (32n x 4 gates), BK=32, 64 tiles.
// 3 LDS buffers (72 KB/block -> 2 blocks/CU = independent barrier domains);
// per tile: [vmcnt(6) -> barrier] -> 12 frag reads -> stage(t+2) -> 32 MFMA.
// Overlap mechanism: the co-resident sibling block is in a different phase,
// so CU-level LDS and matrix pipes run concurrently (m114) without intra-
// block pipelining. Swizzle cg = cL ^ ((row>>2)&3): <=2-way banks (free).
// Wait->barrier->read keeps cross-wave DMA visibility correct (r8 fix).
// ---------------------------------------------------------------------------
#define LD8(base, off) (*reinterpret_cast<const short8*>((base) + (off)))
#define MFMA_(a, b, c) __builtin_amdgcn_mfma_f32_16x16x32_bf16(a, b, c, 0, 0, 0)

__global__ __launch_bounds__(256, 2) void lstm_fused(
    const u16* __restrict__ Ap, const float* __restrict__ c0,
    const u16* __restrict__ Wt, const float* __restrict__ bias,
    float* __restrict__ out) {
  __shared__ u16 As[3][256 * 32];   // 16 KB each
  __shared__ u16 Bs[3][128 * 32];   // 8 KB each   (total 72 KB)

  const int tid = threadIdx.x;
  const int lane = tid & 63;
  const int wid = tid >> 6;
  const int wr = wid >> 1;          // M half (0,1)
  const int wc = wid & 1;           // n-16 block (0,1)
  const int fl = lane & 15;
  const int hi = lane >> 4;

  const int bid0 = blockIdx.x;
  const int sbid = (bid0 & 7) * 64 + (bid0 >> 3);  // XCD swizzle (512%8==0)
  const int m0 = (sbid >> 5) * 256;
  const int n0 = (sbid & 31) * 32;

  // ---- stage maps: A 1024 chunks (4/thread), B 512 (2/thread); linear LDS
  //      dest; global source pre-swizzled: cg = cL ^ ((row>>2)&3).
  // B LDS row = g*32 + wc*16 + u (gate-packed for the fused epilogue).
  int aoff[4], boff[2];
#pragma unroll
  for (int i = 0; i < 4; ++i) {
    const int c = tid + i * 256;
    const int row = c >> 2, cL = c & 3;
    const int cg = cL ^ ((row >> 2) & 3);
    aoff[i] = (m0 + row) * 2048 + cg * 8;
  }
#pragma unroll
  for (int i = 0; i < 2; ++i) {
    const int c = tid + i * 256;
    const int row = c >> 2, cL = c & 3;
    const int cg = cL ^ ((row >> 2) & 3);
    const int ge = row >> 5, rem = row & 31;
    const int wce = rem >> 4, ue = rem & 15;
    boff[i] = (ge * 1024 + n0 + wce * 16 + ue) * 2048 + cg * 8;
  }

  auto stage = [&](int buf, int t) {
    const int k0 = t * 32;
#pragma unroll
    for (int i = 0; i < 4; ++i)
      gl_lds16(Ap + aoff[i] + k0, &As[buf][(tid + i * 256) * 8]);
#pragma unroll
    for (int i = 0; i < 2; ++i)
      gl_lds16(Wt + boff[i] + k0, &Bs[buf][(tid + i * 256) * 8]);
  };

  // ---- fragment read bases (lane-constant swizzle; mi/g-independent) ----
  const int cks = (hi ^ ((fl >> 2) & 3)) * 8;
  const int arow = (wr * 128 + fl) * 32;
  const int brow = (wc * 16 + fl) * 32;   // + g*1024

  f32x4 acc[8][4] = {};   // [mi][gate]

  stage(0, 0);
  stage(1, 1);

  int cur = 0;
  for (int t = 0; t < 64; ++t) {
    if (t < 62) {
      asm volatile("s_waitcnt vmcnt(6)" ::: "memory");  // tile t landed
    } else {
      asm volatile("s_waitcnt vmcnt(0)" ::: "memory");
    }
    __builtin_amdgcn_s_barrier();

    const u16* Ab = &As[cur][0];
    const u16* Bb = &Bs[cur][0];
    short8 af[8], bf[4];
#pragma unroll
    for (int mi = 0; mi < 8; ++mi) af[mi] = LD8(Ab, arow + mi * 512 + cks);
#pragma unroll
    for (int g = 0; g < 4; ++g) bf[g] = LD8(Bb, brow + g * 1024 + cks);

    if (t < 62) {
      const int sb = (cur >= 1) ? cur - 1 : cur + 2;   // (t+2)%3
      stage(sb, t + 2);
    }

#pragma unroll
    for (int mi = 0; mi < 8; ++mi)
#pragma unroll
      for (int g = 0; g < 4; ++g)
        acc[mi][g] = MFMA_(af[mi], bf[g], acc[mi][g]);

    cur = (cur >= 2) ? 0 : cur + 1;
  }

  // ---- fused epilogue: bias + gates + cell update ----
  const int col = n0 + wc * 16 + fl;
  float bv[4];
#pragma unroll
  for (int g = 0; g < 4; ++g) bv[g] = bias[g * 1024 + col];

#pragma unroll
  for (int mi = 0; mi < 8; ++mi) {
#pragma unroll
    for (int r = 0; r < 4; ++r) {
      const int row = m0 + wr * 128 + mi * 16 + hi * 4 + r;
      const float zi = acc[mi][0][r] + bv[0];
      const float zf = acc[mi][1][r] + bv[1];
      const float zg = acc[mi][2][r] + bv[2];
      const float zo = acc[mi][3][r] + bv[3];
      const float ig = 1.f / (1.f + __expf(-zi));
      const float fg = 1.f / (1.f + __expf(-zf));
      const float gg = 1.f - 2.f / (__expf(2.f * zg) + 1.f);  // tanh
      const float og = 1.f / (1.f + __expf(-zo));
      const float c0v = c0[(size_t)row * 1024 + col];
      const float c1 = fg * c0v + ig * gg;
      const float h1 = og * c1;
      out[(size_t)row * 1024 + col] = h1;
      out[(size_t)4194304 + (size_t)row * 1024 + col] = c1;
    }
  }
}

// ---------------------------------------------------------------------------
extern "C" void kernel_launch(void* const* d_in, const int* in_sizes, int n_in,
                              void* d_out, int out_size, void* d_ws, size_t ws_size,
                              hipStream_t stream) {
  const float* x  = (const float*)d_in[0];
  const float* h0 = (const float*)d_in[1];
  const float* c0 = (const float*)d_in[2];
  Ptrs8 w, b;
  for (int i = 0; i < 4; ++i) {
    w.p[i]     = (const float*)d_in[3 + 2 * i];
    b.p[i]     = (const float*)d_in[4 + 2 * i];
    w.p[4 + i] = (const float*)d_in[11 + 2 * i];
    b.p[4 + i] = (const float*)d_in[12 + 2 * i];
  }
  u16* Wt = (u16*)d_ws;                                        // 16 MB
  u16* Ap = (u16*)((char*)d_ws + (size_t)4096 * 2048 * 2);     // 16 MB
  float* bias = (float*)((char*)d_ws + (size_t)2 * 4096 * 2048 * 2);  // 16 KB
  float* out = (float*)d_out;

  prepack<<<6160, 256, 0, stream>>>(w, b, x, h0, Wt, Ap, bias);
  lstm_fused<<<512, 256, 0, stream>>>(Ap, c0, Wt, bias, out);
}

// Round 14
// 92.093 us; speedup vs baseline: 1.0598x; 1.0598x over previous
//
#include <hip/hip_runtime.h>

typedef unsigned short u16;
typedef unsigned int u32;
typedef __attribute__((ext_vector_type(8))) short short8;
typedef __attribute__((ext_vector_type(4))) float f32x4;

__device__ __forceinline__ u16 f2b(float f) {
  u32 u = __builtin_bit_cast(u32, f);
  u32 r = (u + 0x7FFFu + ((u >> 16) & 1u)) >> 16;  // RNE f32->bf16
  return (u16)r;
}

__device__ __forceinline__ void gl_lds16(const void* g, void* l) {
  __builtin_amdgcn_global_load_lds(
      (const __attribute__((address_space(1))) u32*)g,
      (__attribute__((address_space(3))) u32*)l, 16, 0, 0);
}

struct Ptrs8 { const float* p[8]; };

// ---------------------------------------------------------------------------
// Fused pre-pass (one launch): wt_pack | xh_pack | bias by blockIdx range.
// ---------------------------------------------------------------------------
__global__ __launch_bounds__(256) void prepack(Ptrs8 w, Ptrs8 b,
                                               const float* __restrict__ x,
                                               const float* __restrict__ h0,
                                               u16* __restrict__ Wt,
                                               u16* __restrict__ Ap,
                                               float* __restrict__ bias) {
  __shared__ float lds[64 * 64];     // 16 KB (wt branch only)
  const int tid = threadIdx.x;
  const int bid = blockIdx.x;

  if (bid < 2048) {                       // ---- wt_pack ----
    const int mat = bid >> 8;             // 0..7
    const int g = mat & 3, h = mat >> 2;
    const int tile = bid & 255;
    const int kt = tile >> 4, nt = tile & 15;
    const float* __restrict__ src = w.p[mat];
#pragma unroll
    for (int i = 0; i < 4; ++i) {
      int c = tid + i * 256;
      int k = c >> 4, n4 = (c & 15) * 4;
      gl_lds16(src + (size_t)(kt * 64 + k) * 1024 + nt * 64 + n4, &lds[c * 4]);
    }
    asm volatile("s_waitcnt vmcnt(0)");
    __syncthreads();
#pragma unroll
    for (int i = 0; i < 2; ++i) {
      int c = tid + i * 256;
      int n = c & 63, kb = (c >> 6) * 8;
      short8 v;
#pragma unroll
      for (int j = 0; j < 8; ++j) v[j] = (short)f2b(lds[(kb + j) * 64 + n]);
      size_t off = (size_t)(g * 1024 + nt * 64 + n) * 2048 + h * 1024 + kt * 64 + kb;
      *reinterpret_cast<short8*>(Wt + off) = v;
    }
  } else if (bid < 6144) {                // ---- xh_pack ----
    int t = (bid - 2048) * 256 + tid;
    int m = t >> 8, kc = t & 255;
    const float* src = (kc < 128) ? (x + (size_t)m * 1024 + kc * 8)
                                  : (h0 + (size_t)m * 1024 + (kc - 128) * 8);
    float4 a = *reinterpret_cast<const float4*>(src);
    float4 bb = *reinterpret_cast<const float4*>(src + 4);
    short8 v;
    v[0] = (short)f2b(a.x); v[1] = (short)f2b(a.y);
    v[2] = (short)f2b(a.z); v[3] = (short)f2b(a.w);
    v[4] = (short)f2b(bb.x); v[5] = (short)f2b(bb.y);
    v[6] = (short)f2b(bb.z); v[7] = (short)f2b(bb.w);
    *reinterpret_cast<short8*>(Ap + (size_t)m * 2048 + kc * 8) = v;
  } else {                                // ---- bias ----
    int i = (bid - 6144) * 256 + tid;     // 0..4095
    int g = i >> 10, n = i & 1023;
    bias[i] = b.p[g][n] + b.p[4 + g][n];
  }
}

// ---------------------------------------------------------------------------
// Fused LSTM GEMM — half-tile ring pipeline (m201-derived waits):
// 512 thr / 8 waves (2M x 4N), block 256m x (64n x 4 gates), BK=64, 32 tiles.
// 4 phases/tile, ONE barrier per phase:
//   [reads quadrant][stage 1 half of t+1][lgkm0+sched_barrier(0)]
//   [prio1 16 MFMA prio0][vm-wait if due][BAR]
// Half-tile issue order Ah0,Bh0,Ah1,Bh1 (2 loads/thread each). Derived waits:
//   P1-end vmcnt(4)  (retires Ah1(t);  leaves {Bh1(t),Ah0(t+1)})
//   P2-end vmcnt(4)  (retires Bh1(t);  leaves {Ah0,Bh0}(t+1))
//   P3-end none
//   P4-end vmcnt(6)  (retires Ah0,Bh0(t+1); leaves 3 halves flying)
// Flight depth never < 2 halves; waits sit one phase before consumption and
// precede the barrier (cross-wave DMA visibility — r8 rule). Last tile drains
// 2 -> 0. sched_barrier(0) after each bare lgkmcnt(0) stops MFMA hoisting
// (rule 18) — absent from every earlier variant.
// ---------------------------------------------------------------------------
#define LD8(base, off) (*reinterpret_cast<const short8*>((base) + (off)))
#define MFMA_(a, b, c) __builtin_amdgcn_mfma_f32_16x16x32_bf16(a, b, c, 0, 0, 0)
#define BARR __builtin_amdgcn_s_barrier()
#define SB0 __builtin_amdgcn_sched_barrier(0)
#define PRIO1 __builtin_amdgcn_s_setprio(1);
#define PRIO0 __builtin_amdgcn_s_setprio(0);
#define PINM asm volatile("" ::: "memory")

#define READ_A(DST, BASE)                                   \
  _Pragma("unroll")                                         \
  for (int mi = 0; mi < 4; ++mi) {                          \
    DST[mi][0] = LD8(Ab, arow + (BASE + mi) * 1024 + c0k);  \
    DST[mi][1] = LD8(Ab, arow + (BASE + mi) * 1024 + c1k);  \
  }
#define READ_B(DST, GB)                                     \
  _Pragma("unroll")                                         \
  for (int g = 0; g < 2; ++g) {                             \
    DST[g][0] = LD8(Bb, bbase + (GB + g) * 4096 + c0k);     \
    DST[g][1] = LD8(Bb, bbase + (GB + g) * 4096 + c1k);     \
  }
#define MFMA_QUAD(AF, BF, MO, GO)                                              \
  _Pragma("unroll")                                                            \
  for (int mi = 0; mi < 4; ++mi)                                               \
    _Pragma("unroll")                                                          \
    for (int g = 0; g < 2; ++g) {                                              \
      acc[MO + mi][GO + g] = MFMA_(AF[mi][0], BF[g][0], acc[MO + mi][GO + g]); \
      acc[MO + mi][GO + g] = MFMA_(AF[mi][1], BF[g][1], acc[MO + mi][GO + g]); \
    }

// One K-tile. ST: stage t+1. W1/W2/W4: vmcnt at P1/P2/P4 end (-1 = none).
#define TILE4(CUR, T, ST, W1, W2, W4)                                        \
  {                                                                          \
    const int nb = (CUR) ^ 1;                                                \
    const u16* Ab = &As[CUR][0];                                             \
    const u16* Bb = &Bs[CUR][0];                                             \
    short8 af03[4][2], af47[4][2], bf01[2][2], bf23[2][2];                   \
    /* P1: reads Ah0+Bh0 quadrant; stage Ah0(t+1) */                         \
    READ_A(af03, 0) READ_B(bf01, 0)                                          \
    if (ST) stageA(nb, (T) + 1, 0);                                          \
    asm volatile("s_waitcnt lgkmcnt(0)"); SB0;                               \
    PRIO1 MFMA_QUAD(af03, bf01, 0, 0) PRIO0                                  \
    if ((W1) == 4) asm volatile("s_waitcnt vmcnt(4)" ::: "memory");          \
    else if ((W1) == 2) asm volatile("s_waitcnt vmcnt(2)" ::: "memory");     \
    else PINM;                                                               \
    BARR;                                                                    \
    /* P2: reads Ah1; stage Bh0(t+1) */                                      \
    READ_A(af47, 4)                                                          \
    if (ST) stageB(nb, (T) + 1, 0);                                          \
    asm volatile("s_waitcnt lgkmcnt(0)"); SB0;                               \
    PRIO1 MFMA_QUAD(af47, bf01, 4, 0) PRIO0                                  \
    if ((W2) == 4) asm volatile("s_waitcnt vmcnt(4)" ::: "memory");          \
    else if ((W2) == 0) asm volatile("s_waitcnt vmcnt(0)" ::: "memory");     \
    else PINM;                                                               \
    BARR;                                                                    \
    /* P3: reads Bh1; stage Ah1(t+1) */                                      \
    READ_B(bf23, 2)                                                          \
    if (ST) stageA(nb, (T) + 1, 1);                                          \
    asm volatile("s_waitcnt lgkmcnt(0)"); SB0;                               \
    PRIO1 MFMA_QUAD(af03, bf23, 0, 2) PRIO0                                  \
    PINM;                                                                    \
    BARR;                                                                    \
    /* P4: no reads; stage Bh1(t+1) */                                       \
    if (ST) stageB(nb, (T) + 1, 1);                                          \
    PRIO1 MFMA_QUAD(af47, bf23, 4, 2) PRIO0                                  \
    if ((W4) == 6) asm volatile("s_waitcnt vmcnt(6)" ::: "memory");          \
    else PINM;                                                               \
    BARR;                                                                    \
  }

__global__ __launch_bounds__(512, 2) void lstm_fused(
    const u16* __restrict__ Ap, const float* __restrict__ c0,
    const u16* __restrict__ Wt, const float* __restrict__ bias,
    float* __restrict__ out) {
  __shared__ u16 As[2][256 * 64];   // 32 KB each
  __shared__ u16 Bs[2][256 * 64];   // 32 KB each

  const int tid = threadIdx.x;
  const int lane = tid & 63;
  const int wid = tid >> 6;
  const int wr = wid >> 2;          // M half
  const int wc = wid & 3;           // n-16 block
  const int fl = lane & 15;
  const int hi = lane >> 4;
  const int lo7 = fl & 7;

  const int bid0 = blockIdx.x;
  const int sbid = (bid0 & 7) * 32 + (bid0 >> 3);  // XCD swizzle (256%8==0)
  const int m0 = (sbid >> 4) * 256;
  const int n0 = (sbid & 15) * 64;

  // stage maps: 2048 16B-chunks/tile, 4/thread, linear LDS dest, source
  // pre-swizzled cg = cL ^ (row & 7). A group i: rows [i*64,(i+1)*64);
  // Ah0 = groups {0,2} (mi 0-3 of both wr), Ah1 = {1,3}.
  // B LDS row = g*64 + wc*16 + u; group i = gate i; Bh0 = {0,1}, Bh1 = {2,3}.
  int aoff[4], boff[4];
#pragma unroll
  for (int i = 0; i < 4; ++i) {
    const int L = tid + i * 512;
    const int r = L >> 3, cL = L & 7;
    const int cg = cL ^ (r & 7);
    aoff[i] = (m0 + r) * 2048 + cg * 8;
    const int ge = r >> 6, wce = (r >> 4) & 3, ue = r & 15;
    boff[i] = (ge * 1024 + n0 + wce * 16 + ue) * 2048 + cg * 8;
  }

  auto stageA = [&](int buf, int t, int h) {  // half h: groups {h, h+2}
    const int k0 = t * 64;
    gl_lds16(Ap + aoff[h] + k0, &As[buf][(tid + h * 512) * 8]);
    gl_lds16(Ap + aoff[h + 2] + k0, &As[buf][(tid + (h + 2) * 512) * 8]);
  };
  auto stageB = [&](int buf, int t, int h) {  // half h: groups {2h, 2h+1}
    const int k0 = t * 64;
    gl_lds16(Wt + boff[2 * h] + k0, &Bs[buf][(tid + (2 * h) * 512) * 8]);
    gl_lds16(Wt + boff[2 * h + 1] + k0, &Bs[buf][(tid + (2 * h + 1) * 512) * 8]);
  };

  // fragment read bases (lane-constant swizzle)
  const int c0k = (hi ^ lo7) * 8;
  const int c1k = ((4 + hi) ^ lo7) * 8;
  const int arow = (wr * 128 + fl) * 64;
  const int bbase = (wc * 16 + fl) * 64;   // + g*4096

  f32x4 acc[8][4] = {};   // [mi][gate]

  // prologue: tile 0 halves in consumption order; retire Ah0,Bh0
  stageA(0, 0, 0);
  stageB(0, 0, 0);
  stageA(0, 0, 1);
  stageB(0, 0, 1);
  asm volatile("s_waitcnt vmcnt(4)" ::: "memory");
  BARR;

  for (int t = 0; t < 31; ++t) {
    TILE4(t & 1, t, 1, 4, 4, 6)
  }
  TILE4(1, 31, 0, 2, 0, -1)   // drain: 2 -> 0

  // ---- fused epilogue: bias + gates + cell update ----
  const int col = n0 + wc * 16 + fl;
  float bv[4];
#pragma unroll
  for (int g = 0; g < 4; ++g) bv[g] = bias[g * 1024 + col];

#pragma unroll
  for (int mi = 0; mi < 8; ++mi) {
#pragma unroll
    for (int r = 0; r < 4; ++r) {
      const int row = m0 + wr * 128 + mi * 16 + hi * 4 + r;
      const float zi = acc[mi][0][r] + bv[0];
      const float zf = acc[mi][1][r] + bv[1];
      const float zg = acc[mi][2][r] + bv[2];
      const float zo = acc[mi][3][r] + bv[3];
      const float ig = 1.f / (1.f + __expf(-zi));
      const float fg = 1.f / (1.f + __expf(-zf));
      const float gg = 1.f - 2.f / (__expf(2.f * zg) + 1.f);  // tanh
      const float og = 1.f / (1.f + __expf(-zo));
      const float c0v = c0[(size_t)row * 1024 + col];
      const float c1 = fg * c0v + ig * gg;
      const float h1 = og * c1;
      out[(size_t)row * 1024 + col] = h1;
      out[(size_t)4194304 + (size_t)row * 1024 + col] = c1;
    }
  }
}

// ---------------------------------------------------------------------------
extern "C" void kernel_launch(void* const* d_in, const int* in_sizes, int n_in,
                              void* d_out, int out_size, void* d_ws, size_t ws_size,
                              hipStream_t stream) {
  const float* x  = (const float*)d_in[0];
  const float* h0 = (const float*)d_in[1];
  const float* c0 = (const float*)d_in[2];
  Ptrs8 w, b;
  for (int i = 0; i < 4; ++i) {
    w.p[i]     = (const float*)d_in[3 + 2 * i];
    b.p[i]     = (const float*)d_in[4 + 2 * i];
    w.p[4 + i] = (const float*)d_in[11 + 2 * i];
    b.p[4 + i] = (const float*)d_in[12 + 2 * i];
  }
  u16* Wt = (u16*)d_ws;                                        // 16 MB
  u16* Ap = (u16*)((char*)d_ws + (size_t)4096 * 2048 * 2);     // 16 MB
  float* bias = (float*)((char*)d_ws + (size_t)2 * 4096 * 2048 * 2);  // 16 KB
  float* out = (float*)d_out;

  prepack<<<6160, 256, 0, stream>>>(w, b, x, h0, Wt, Ap, bias);
  lstm_fused<<<256, 512, 0, stream>>>(Ap, c0, Wt, bias, out);
}